// Round 1
// baseline (456.833 us; speedup 1.0000x reference)
//
#include <hip/hip_runtime.h>
#include <math.h>

#define N_SAMP 65536
#define DIM    512
#define NCLS   64
#define KSEL   64

// workspace layout (bytes)
#define OFF_COUNTS   0u          // 64 int
#define OFF_CSUM     256u        // 64*512 f32
#define OFF_CENTERS  131328u     // 64*512 f32
#define OFF_C2       262400u     // 64 f32
#define OFF_MEANS    262656u     // 128 f32 (pos[64], neg[64])
#define OFF_DIST     263168u     // 64*65536 f32

// ---------------------------------------------------------------- init
__global__ __launch_bounds__(256) void k_init(int* __restrict__ counts, float* __restrict__ csum) {
  int i = blockIdx.x * 256 + threadIdx.x;
  if (i < NCLS) counts[i] = 0;
  for (int j = i; j < NCLS * DIM; j += gridDim.x * 256) csum[j] = 0.f;
}

// ------------------------------------------------- class partial sums
// grid: 64 classes * 16 row-ranges; block 256 (4 waves, each owns 128 dims)
__global__ __launch_bounds__(256) void k_class_sums(const float* __restrict__ x,
                                                    const int* __restrict__ y,
                                                    float* __restrict__ csum,
                                                    int* __restrict__ counts) {
  __shared__ int list[4096];
  __shared__ int lcnt;
  const int c  = blockIdx.x >> 4;
  const int r0 = (blockIdx.x & 15) * 4096;
  const int tid = threadIdx.x;
  if (tid == 0) lcnt = 0;
  __syncthreads();
  for (int i = tid; i < 4096; i += 256) {
    if (y[r0 + i] == c) { int p = atomicAdd(&lcnt, 1); list[p] = r0 + i; }
  }
  __syncthreads();
  const int n = lcnt;
  const int dbase = (tid >> 6) * 128 + (tid & 63) * 2;
  float a0 = 0.f, a1 = 0.f, b0 = 0.f, b1 = 0.f;
  int i = 0;
  for (; i + 2 <= n; i += 2) {
    const float* p0 = x + (size_t)list[i] * DIM + dbase;
    const float* p1 = x + (size_t)list[i + 1] * DIM + dbase;
    a0 += p0[0]; a1 += p0[1];
    b0 += p1[0]; b1 += p1[1];
  }
  if (i < n) { const float* p0 = x + (size_t)list[i] * DIM + dbase; a0 += p0[0]; a1 += p0[1]; }
  a0 += b0; a1 += b1;
  atomicAdd(&csum[c * DIM + dbase], a0);
  atomicAdd(&csum[c * DIM + dbase + 1], a1);
  if (tid == 0) atomicAdd(&counts[c], n);
}

// ------------------------------------------------- finalize centers + c2
__global__ __launch_bounds__(64) void k_centers(const float* __restrict__ csum,
                                                const int* __restrict__ counts,
                                                float* __restrict__ centers,
                                                float* __restrict__ c2) {
  const int c = blockIdx.x, l = threadIdx.x;
  const float inv = 1.0f / (float)counts[c];
  float ss = 0.f;
  #pragma unroll
  for (int j = 0; j < 8; ++j) {
    int d = j * 64 + l;
    float v = csum[c * DIM + d] * inv;
    centers[c * DIM + d] = v;
    ss += v * v;
  }
  #pragma unroll
  for (int o = 32; o; o >>= 1) ss += __shfl_down(ss, o, 64);
  if (l == 0) c2[c] = ss;
}

// ------------------------------------------------- distances [C][N]
// grid 512: 128 samples/block; thread owns 1 sample x 32 classes.
#define TSAMP 128
#define KSTEP 64
#define XSTR  68   // LDS row stride in floats (16B-aligned, breaks bank pathology)
__global__ __launch_bounds__(256, 2) void k_dist(const float* __restrict__ x,
                                                 const float* __restrict__ centers,
                                                 const float* __restrict__ c2,
                                                 float* __restrict__ dist) {
  __shared__ float xt[TSAMP * XSTR];
  const int tid = threadIdx.x;
  const int s0 = blockIdx.x * TSAMP;
  const int s = tid & 127;
  int hh = tid >> 7;                         // wave-uniform (0 or 1)
  hh = __builtin_amdgcn_readfirstlane(hh);
  const float* __restrict__ cen = centers + (size_t)hh * 32 * DIM;

  float acc[32];
  #pragma unroll
  for (int i = 0; i < 32; ++i) acc[i] = 0.f;
  float x2 = 0.f;

  for (int kk = 0; kk < DIM; kk += KSTEP) {
    __syncthreads();
    #pragma unroll
    for (int i = 0; i < 8; ++i) {            // stage [128][64] tile
      int idx = tid + i * 256;
      int row = idx >> 4, c4 = idx & 15;
      const float4 v = *reinterpret_cast<const float4*>(x + (size_t)(s0 + row) * DIM + kk + c4 * 4);
      *reinterpret_cast<float4*>(&xt[row * XSTR + c4 * 4]) = v;
    }
    __syncthreads();
    float4 xv[16];
    #pragma unroll
    for (int j = 0; j < 16; ++j) xv[j] = *reinterpret_cast<const float4*>(&xt[s * XSTR + j * 4]);
    #pragma unroll
    for (int j = 0; j < 16; ++j)
      x2 += xv[j].x * xv[j].x + xv[j].y * xv[j].y + xv[j].z * xv[j].z + xv[j].w * xv[j].w;
    #pragma unroll
    for (int cc = 0; cc < 32; ++cc) {
      const float* __restrict__ cp = cen + cc * DIM + kk;   // wave-uniform -> s_load
      float a = acc[cc];
      #pragma unroll
      for (int j = 0; j < 16; ++j) {
        a = fmaf(cp[j * 4 + 0], xv[j].x, a);
        a = fmaf(cp[j * 4 + 1], xv[j].y, a);
        a = fmaf(cp[j * 4 + 2], xv[j].z, a);
        a = fmaf(cp[j * 4 + 3], xv[j].w, a);
      }
      acc[cc] = a;
    }
  }
  #pragma unroll
  for (int cc = 0; cc < 32; ++cc) {
    int C_ = hh * 32 + cc;
    float d2 = c2[C_] + x2 - 2.0f * acc[cc];
    d2 = fmaxf(d2, 1e-12f);
    dist[(size_t)C_ * N_SAMP + s0 + s] = sqrtf(d2);
  }
}

// ------------------------------------------------- top-k selection
// 6-way fused block reduction: slots {sum,sum,min,max,sum,sum}
__device__ __forceinline__ void redSix(float v0, float v1, float v2, float v3, float v4, float v5,
                                       float* redf, float* bcast) {
  #pragma unroll
  for (int o = 32; o; o >>= 1) {
    v0 += __shfl_xor(v0, o, 64);
    v1 += __shfl_xor(v1, o, 64);
    v2 = fminf(v2, __shfl_xor(v2, o, 64));
    v3 = fmaxf(v3, __shfl_xor(v3, o, 64));
    v4 += __shfl_xor(v4, o, 64);
    v5 += __shfl_xor(v5, o, 64);
  }
  const int wid = threadIdx.x >> 6;
  if ((threadIdx.x & 63) == 0) {
    redf[wid] = v0; redf[16 + wid] = v1; redf[32 + wid] = v2;
    redf[48 + wid] = v3; redf[64 + wid] = v4; redf[80 + wid] = v5;
  }
  __syncthreads();
  if (threadIdx.x < 16) {
    const int l = threadIdx.x;
    float a0 = redf[l], a1 = redf[16 + l], a2 = redf[32 + l],
          a3 = redf[48 + l], a4 = redf[64 + l], a5 = redf[80 + l];
    #pragma unroll
    for (int o = 8; o; o >>= 1) {
      a0 += __shfl_xor(a0, o, 64);
      a1 += __shfl_xor(a1, o, 64);
      a2 = fminf(a2, __shfl_xor(a2, o, 64));
      a3 = fmaxf(a3, __shfl_xor(a3, o, 64));
      a4 += __shfl_xor(a4, o, 64);
      a5 += __shfl_xor(a5, o, 64);
    }
    if (l == 0) { bcast[0]=a0; bcast[1]=a1; bcast[2]=a2; bcast[3]=a3; bcast[4]=a4; bcast[5]=a5; }
  }
  __syncthreads();
}

// grid 128: block b -> class b>>1, (b&1)? k-smallest among non-members : k-largest among members.
__global__ __launch_bounds__(1024) void k_select(const float* __restrict__ dist,
                                                 const int* __restrict__ y,
                                                 float* __restrict__ means) {
  __shared__ unsigned bitmap[2048];
  __shared__ unsigned hist[1024];
  __shared__ float redf[96];
  __shared__ float bcast[8];
  __shared__ int bsel;

  const int tid = threadIdx.x;
  const int c = blockIdx.x >> 1;
  const int neg = blockIdx.x & 1;
  const float* __restrict__ row = dist + (size_t)c * N_SAMP;

  #pragma unroll
  for (int j = 0; j < 2; ++j) {              // membership bitmap, no atomics
    unsigned wbits = 0u;
    const int base = tid * 64 + j * 32;
    #pragma unroll
    for (int b = 0; b < 32; ++b) wbits |= (unsigned)(y[base + b] == c) << b;
    bitmap[tid * 2 + j] = wbits;
  }
  __syncthreads();

  const float qnan = __uint_as_float(0x7fc00000u);
  float vals[64];
  float mn = 1e30f, mx = -1e30f;
  #pragma unroll
  for (int i = 0; i < 64; ++i) {
    const int n = i * 1024 + tid;
    const unsigned bit = (bitmap[n >> 5] >> (n & 31)) & 1u;
    float v = row[n];
    if (!neg) v = -v;                         // pos: largest dist == smallest -dist
    const float vv = ((int)bit != neg) ? v : qnan;   // NaN self-excludes everywhere
    vals[i] = vv;
    mn = fminf(mn, vv);
    mx = fmaxf(mx, vv);
  }

  redSix(0.f, 0.f, mn, mx, 0.f, 0.f, redf, bcast);
  float lo = bcast[2], hi = bcast[3];
  float sum_acc = 0.f;
  int rem = KSEL;

  for (int iter = 0; iter < 8 && rem > 0; ++iter) {
    if (!(hi > lo)) { sum_acc += (float)rem * lo; rem = 0; break; }
    const float width = hi - lo;
    const float scale = 1024.0f / width;
    hist[tid] = 0u;
    __syncthreads();
    #pragma unroll
    for (int i = 0; i < 64; ++i) {
      const float v = vals[i];
      if (v >= lo && v <= hi) {
        int b = (int)((v - lo) * scale);
        b = b < 1023 ? b : 1023;
        b = b > 0 ? b : 0;
        atomicAdd(&hist[b], 1u);
      }
    }
    __syncthreads();
    for (int off = 1; off < 1024; off <<= 1) {     // inclusive scan
      const unsigned t = (tid >= off) ? hist[tid - off] : 0u;
      __syncthreads();
      hist[tid] += t;
      __syncthreads();
    }
    if (tid == 0) bsel = 1023;
    __syncthreads();
    {
      const unsigned cumt = hist[tid];
      const unsigned cumprev = (tid == 0) ? 0u : hist[tid - 1];
      if (cumt >= (unsigned)rem && cumprev < (unsigned)rem) bsel = tid;
    }
    __syncthreads();
    const int B = bsel;
    const bool lastbin = (B == 1023);
    const float new_lo = lo + (float)B * width * (1.0f / 1024.0f);
    const float new_hi = lastbin ? hi : lo + (float)(B + 1) * width * (1.0f / 1024.0f);

    // exact interval pass (histogram is only a split heuristic)
    float sb = 0.f, si = 0.f, mi = 1e30f, ma = -1e30f, cb = 0.f, ci = 0.f;
    #pragma unroll
    for (int i = 0; i < 64; ++i) {
      const float v = vals[i];
      if (v >= lo && v < new_lo) { sb += v; cb += 1.f; }
      const bool inr = (v >= new_lo) && (lastbin ? (v <= hi) : (v < new_hi));
      if (inr) { si += v; ci += 1.f; mi = fminf(mi, v); ma = fmaxf(ma, v); }
    }
    redSix(sb, si, mi, ma, cb, ci, redf, bcast);
    const float SB = bcast[0], SI = bcast[1], MI = bcast[2], MA = bcast[3];
    const int CB = (int)bcast[4], CI = (int)bcast[5];

    if (CB >= rem) { hi = new_lo; continue; }
    sum_acc += SB; rem -= CB;
    if (rem == 0) break;
    if (CI <= rem) {
      sum_acc += SI; rem -= CI;
      if (rem == 0) break;
      if (lastbin) break;
      lo = new_hi;
      continue;
    }
    if (!(MA > MI)) { sum_acc += (float)rem * MI; rem = 0; break; }
    lo = MI; hi = MA;
  }

  // guaranteed-terminating exact peel fallback
  for (int guard = 0; guard < 100 && rem > 0; ++guard) {
    float m = 1e30f;
    #pragma unroll
    for (int i = 0; i < 64; ++i) {
      const float v = vals[i];
      if (v >= lo && v <= hi) m = fminf(m, v);
    }
    redSix(0.f, 0.f, m, 0.f, 0.f, 0.f, redf, bcast);
    const float M = bcast[2];
    if (M >= 1e29f) break;
    float ce = 0.f;
    #pragma unroll
    for (int i = 0; i < 64; ++i) if (vals[i] == M) ce += 1.f;
    redSix(0.f, 0.f, 0.f, 0.f, ce, 0.f, redf, bcast);
    const int CE = (int)bcast[4];
    const int take = rem < CE ? rem : CE;
    sum_acc += (float)take * M;
    rem -= take;
    unsigned bu = __float_as_uint(M);
    bu = (M < 0.f) ? bu - 1u : bu + 1u;      // nextafter(+inf) for nonzero floats
    lo = __uint_as_float(bu);
  }

  if (tid == 0) {
    const float s = neg ? sum_acc : -sum_acc;
    means[neg * 64 + c] = s * (1.0f / 64.0f);
  }
}

// ------------------------------------------------- final loss
__global__ __launch_bounds__(64) void k_loss(const float* __restrict__ means, float* __restrict__ out) {
  const int c = threadIdx.x;
  float pc = fmaxf(1.0f + means[c] - means[64 + c], 0.0f);
  #pragma unroll
  for (int o = 32; o; o >>= 1) pc += __shfl_down(pc, o, 64);
  if (c == 0) out[0] = pc * (1.0f / 4096.0f);
}

// ----------------------------------------------------------------------
extern "C" void kernel_launch(void* const* d_in, const int* in_sizes, int n_in,
                              void* d_out, int out_size, void* d_ws, size_t ws_size,
                              hipStream_t stream) {
  const float* x = (const float*)d_in[0];
  const int* y = (const int*)d_in[1];
  float* out = (float*)d_out;
  char* w = (char*)d_ws;
  int* counts   = (int*)(w + OFF_COUNTS);
  float* csum    = (float*)(w + OFF_CSUM);
  float* centers = (float*)(w + OFF_CENTERS);
  float* c2      = (float*)(w + OFF_C2);
  float* means   = (float*)(w + OFF_MEANS);
  float* dist    = (float*)(w + OFF_DIST);

  hipLaunchKernelGGL(k_init, dim3(128), dim3(256), 0, stream, counts, csum);
  hipLaunchKernelGGL(k_class_sums, dim3(1024), dim3(256), 0, stream, x, y, csum, counts);
  hipLaunchKernelGGL(k_centers, dim3(64), dim3(64), 0, stream, csum, counts, centers, c2);
  hipLaunchKernelGGL(k_dist, dim3(N_SAMP / TSAMP), dim3(256), 0, stream, x, centers, c2, dist);
  hipLaunchKernelGGL(k_select, dim3(128), dim3(1024), 0, stream, dist, y, means);
  hipLaunchKernelGGL(k_loss, dim3(1), dim3(64), 0, stream, means, out);
}

// Round 2
// 271.365 us; speedup vs baseline: 1.6835x; 1.6835x over previous
//
#include <hip/hip_runtime.h>
#include <math.h>

#define N_SAMP 65536
#define DIM    512
#define NCLS   64
#define KSEL   64
#define NBIN   1024
#define BCAP   256

// workspace layout (bytes)
#define OFF_COUNTS   0u           // 64 i32
#define OFF_CSUM     256u         // 64*512 f32
#define OFF_CENTERS  131328u      // 64*512 f32
#define OFF_C2       262400u      // 64 f32
#define OFF_MEANS    262656u      // 128 f32 (pos[0..63], neg[64..127])
#define OFF_DIST     263168u      // 64*65536 f32  -> ends 17040384
#define OFF_STATS    17040384u    // 64*4 u32 {pmin,pmax,nmin,nmax} (float bits, dist>=0)
#define OFF_HIST     17041408u    // 64*2*1024 u32
#define OFF_THRESH   17565696u    // 128 * uint4 {T, strict_cnt, done, mean_bits}
#define OFF_SSUM     17569792u    // 128 f32 strict sums
#define OFF_BCNT     17570304u    // 128 i32 boundary counters
#define OFF_BBUF     17570816u    // 128 * 256 f32 boundary values

// ---------------------------------------------------------------- init
__global__ __launch_bounds__(256) void k_init(int* __restrict__ counts,
                                              float* __restrict__ csum,
                                              unsigned* __restrict__ stats,
                                              unsigned* __restrict__ ghist,
                                              float* __restrict__ ssum,
                                              int* __restrict__ bcnt) {
  const int i = blockIdx.x * 256 + threadIdx.x;
  const int stride = gridDim.x * 256;
  if (i < NCLS) counts[i] = 0;
  for (int j = i; j < NCLS * DIM; j += stride) csum[j] = 0.f;
  for (int j = i; j < NCLS * 4; j += stride) stats[j] = (j & 1) ? 0u : 0xFFFFFFFFu; // even=min slot, odd=max slot
  for (int j = i; j < NCLS * 2 * NBIN; j += stride) ghist[j] = 0u;
  for (int j = i; j < 128; j += stride) { ssum[j] = 0.f; bcnt[j] = 0; }
}

// ------------------------------------------------- class partial sums
__global__ __launch_bounds__(256) void k_class_sums(const float* __restrict__ x,
                                                    const int* __restrict__ y,
                                                    float* __restrict__ csum,
                                                    int* __restrict__ counts) {
  __shared__ int list[4096];
  __shared__ int lcnt;
  const int c  = blockIdx.x >> 4;
  const int r0 = (blockIdx.x & 15) * 4096;
  const int tid = threadIdx.x;
  if (tid == 0) lcnt = 0;
  __syncthreads();
  for (int i = tid; i < 4096; i += 256) {
    if (y[r0 + i] == c) { int p = atomicAdd(&lcnt, 1); list[p] = r0 + i; }
  }
  __syncthreads();
  const int n = lcnt;
  const int dbase = (tid >> 6) * 128 + (tid & 63) * 2;
  float a0 = 0.f, a1 = 0.f, b0 = 0.f, b1 = 0.f;
  int i = 0;
  for (; i + 2 <= n; i += 2) {
    const float* p0 = x + (size_t)list[i] * DIM + dbase;
    const float* p1 = x + (size_t)list[i + 1] * DIM + dbase;
    a0 += p0[0]; a1 += p0[1];
    b0 += p1[0]; b1 += p1[1];
  }
  if (i < n) { const float* p0 = x + (size_t)list[i] * DIM + dbase; a0 += p0[0]; a1 += p0[1]; }
  a0 += b0; a1 += b1;
  atomicAdd(&csum[c * DIM + dbase], a0);
  atomicAdd(&csum[c * DIM + dbase + 1], a1);
  if (tid == 0) atomicAdd(&counts[c], n);
}

// ------------------------------------------------- finalize centers + c2
__global__ __launch_bounds__(64) void k_centers(const float* __restrict__ csum,
                                                const int* __restrict__ counts,
                                                float* __restrict__ centers,
                                                float* __restrict__ c2) {
  const int c = blockIdx.x, l = threadIdx.x;
  const float inv = 1.0f / (float)counts[c];
  float ss = 0.f;
  #pragma unroll
  for (int j = 0; j < 8; ++j) {
    int d = j * 64 + l;
    float v = csum[c * DIM + d] * inv;
    centers[c * DIM + d] = v;
    ss += v * v;
  }
  #pragma unroll
  for (int o = 32; o; o >>= 1) ss += __shfl_down(ss, o, 64);
  if (l == 0) c2[c] = ss;
}

// ------------------------------------------------- distances [C][N]
#define TSAMP 128
#define KSTEP 64
#define XSTR  68
__global__ __launch_bounds__(256, 2) void k_dist(const float* __restrict__ x,
                                                 const float* __restrict__ centers,
                                                 const float* __restrict__ c2,
                                                 float* __restrict__ dist) {
  __shared__ float xt[TSAMP * XSTR];
  const int tid = threadIdx.x;
  const int s0 = blockIdx.x * TSAMP;
  const int s = tid & 127;
  int hh = tid >> 7;
  hh = __builtin_amdgcn_readfirstlane(hh);
  const float* __restrict__ cen = centers + (size_t)hh * 32 * DIM;

  float acc[32];
  #pragma unroll
  for (int i = 0; i < 32; ++i) acc[i] = 0.f;
  float x2 = 0.f;

  for (int kk = 0; kk < DIM; kk += KSTEP) {
    __syncthreads();
    #pragma unroll
    for (int i = 0; i < 8; ++i) {
      int idx = tid + i * 256;
      int row = idx >> 4, c4 = idx & 15;
      const float4 v = *reinterpret_cast<const float4*>(x + (size_t)(s0 + row) * DIM + kk + c4 * 4);
      *reinterpret_cast<float4*>(&xt[row * XSTR + c4 * 4]) = v;
    }
    __syncthreads();
    float4 xv[16];
    #pragma unroll
    for (int j = 0; j < 16; ++j) xv[j] = *reinterpret_cast<const float4*>(&xt[s * XSTR + j * 4]);
    #pragma unroll
    for (int j = 0; j < 16; ++j)
      x2 += xv[j].x * xv[j].x + xv[j].y * xv[j].y + xv[j].z * xv[j].z + xv[j].w * xv[j].w;
    #pragma unroll
    for (int cc = 0; cc < 32; ++cc) {
      const float* __restrict__ cp = cen + cc * DIM + kk;
      float a = acc[cc];
      #pragma unroll
      for (int j = 0; j < 16; ++j) {
        a = fmaf(cp[j * 4 + 0], xv[j].x, a);
        a = fmaf(cp[j * 4 + 1], xv[j].y, a);
        a = fmaf(cp[j * 4 + 2], xv[j].z, a);
        a = fmaf(cp[j * 4 + 3], xv[j].w, a);
      }
      acc[cc] = a;
    }
  }
  #pragma unroll
  for (int cc = 0; cc < 32; ++cc) {
    int C_ = hh * 32 + cc;
    float d2 = c2[C_] + x2 - 2.0f * acc[cc];
    d2 = fmaxf(d2, 1e-12f);
    dist[(size_t)C_ * N_SAMP + s0 + s] = sqrtf(d2);
  }
}

// ------------------------------------------------- helpers
__device__ __forceinline__ unsigned wredMinU(unsigned v) {
  #pragma unroll
  for (int o = 32; o; o >>= 1) { unsigned t = (unsigned)__shfl_xor((int)v, o, 64); v = v < t ? v : t; }
  return v;
}
__device__ __forceinline__ unsigned wredMaxU(unsigned v) {
  #pragma unroll
  for (int o = 32; o; o >>= 1) { unsigned t = (unsigned)__shfl_xor((int)v, o, 64); v = v > t ? v : t; }
  return v;
}
__device__ __forceinline__ float wredAddF(float v) {
  #pragma unroll
  for (int o = 32; o; o >>= 1) v += __shfl_xor(v, o, 64);
  return v;
}
__device__ __forceinline__ int binOf(float v, float mn, float scale) {
  int b = (int)((v - mn) * scale);
  b = b < NBIN - 1 ? b : NBIN - 1;
  return b > 0 ? b : 0;
}

// ------------------------------------------------- per-(class,role) min/max
// grid 1024: (c = bx>>4, chunk = bx&15), 256 threads, 4096 samples/chunk
__global__ __launch_bounds__(256) void k_stats(const float* __restrict__ dist,
                                               const int* __restrict__ y,
                                               unsigned* __restrict__ stats) {
  __shared__ unsigned red[4][4];
  const int tid = threadIdx.x;
  const int c = blockIdx.x >> 4;
  const int n0 = (blockIdx.x & 15) * 4096;
  const float4* __restrict__ row4 = (const float4*)(dist + (size_t)c * N_SAMP + n0);
  const int4* __restrict__ y4 = (const int4*)(y + n0);
  unsigned pmin = 0xFFFFFFFFu, pmax = 0u, nmin = 0xFFFFFFFFu, nmax = 0u;
  #pragma unroll
  for (int i = 0; i < 4; ++i) {
    const int idx = i * 256 + tid;
    const float4 v = row4[idx];
    const int4 yy = y4[idx];
    const float vv[4] = {v.x, v.y, v.z, v.w};
    const int ys[4] = {yy.x, yy.y, yy.z, yy.w};
    #pragma unroll
    for (int j = 0; j < 4; ++j) {
      const unsigned b = __float_as_uint(vv[j]);
      if (ys[j] == c) { pmin = b < pmin ? b : pmin; pmax = b > pmax ? b : pmax; }
      else            { nmin = b < nmin ? b : nmin; nmax = b > nmax ? b : nmax; }
    }
  }
  pmin = wredMinU(pmin); pmax = wredMaxU(pmax);
  nmin = wredMinU(nmin); nmax = wredMaxU(nmax);
  const int wid = tid >> 6;
  if ((tid & 63) == 0) { red[wid][0] = pmin; red[wid][1] = pmax; red[wid][2] = nmin; red[wid][3] = nmax; }
  __syncthreads();
  if (tid == 0) {
    unsigned a0 = red[0][0], a1 = red[0][1], a2 = red[0][2], a3 = red[0][3];
    #pragma unroll
    for (int w = 1; w < 4; ++w) {
      a0 = red[w][0] < a0 ? red[w][0] : a0;
      a1 = red[w][1] > a1 ? red[w][1] : a1;
      a2 = red[w][2] < a2 ? red[w][2] : a2;
      a3 = red[w][3] > a3 ? red[w][3] : a3;
    }
    atomicMin(&stats[c * 4 + 0], a0);
    atomicMax(&stats[c * 4 + 1], a1);
    atomicMin(&stats[c * 4 + 2], a2);
    atomicMax(&stats[c * 4 + 3], a3);
  }
}

// ------------------------------------------------- adaptive histograms
__global__ __launch_bounds__(256) void k_hist(const float* __restrict__ dist,
                                              const int* __restrict__ y,
                                              const unsigned* __restrict__ stats,
                                              unsigned* __restrict__ ghist) {
  __shared__ unsigned lh[2 * NBIN];
  const int tid = threadIdx.x;
  const int c = blockIdx.x >> 4;
  const int n0 = (blockIdx.x & 15) * 4096;
  for (int i = tid; i < 2 * NBIN; i += 256) lh[i] = 0u;
  const float mnp = __uint_as_float(stats[c * 4 + 0]);
  const float mxp = __uint_as_float(stats[c * 4 + 1]);
  const float mnn = __uint_as_float(stats[c * 4 + 2]);
  const float mxn = __uint_as_float(stats[c * 4 + 3]);
  const float scp = (mxp > mnp) ? (float)NBIN / (mxp - mnp) : 0.f;
  const float scn = (mxn > mnn) ? (float)NBIN / (mxn - mnn) : 0.f;
  __syncthreads();
  const float4* __restrict__ row4 = (const float4*)(dist + (size_t)c * N_SAMP + n0);
  const int4* __restrict__ y4 = (const int4*)(y + n0);
  #pragma unroll
  for (int i = 0; i < 4; ++i) {
    const int idx = i * 256 + tid;
    const float4 v = row4[idx];
    const int4 yy = y4[idx];
    const float vv[4] = {v.x, v.y, v.z, v.w};
    const int ys[4] = {yy.x, yy.y, yy.z, yy.w};
    #pragma unroll
    for (int j = 0; j < 4; ++j) {
      if (ys[j] == c) atomicAdd(&lh[binOf(vv[j], mnp, scp)], 1u);
      else            atomicAdd(&lh[NBIN + binOf(vv[j], mnn, scn)], 1u);
    }
  }
  __syncthreads();
  for (int i = tid; i < 2 * NBIN; i += 256) {
    const unsigned v = lh[i];
    if (v) atomicAdd(&ghist[c * 2 * NBIN + i], v);
  }
}

// ------------------------------------------------- find boundary bin per (c,role)
// grid 128: c = bx>>1, role = bx&1 (0=pos largest-members, 1=neg smallest-nonmembers)
__global__ __launch_bounds__(256) void k_thresh(const unsigned* __restrict__ ghist,
                                                const unsigned* __restrict__ stats,
                                                uint4* __restrict__ trec) {
  __shared__ unsigned wsum[4];
  const int tid = threadIdx.x;
  const int c = blockIdx.x >> 1;
  const int role = blockIdx.x & 1;
  const float mn = __uint_as_float(stats[c * 4 + role * 2]);
  const float mx = __uint_as_float(stats[c * 4 + role * 2 + 1]);
  if (!(mx > mn)) {
    if (tid == 0) trec[c * 2 + role] = make_uint4(0u, 0u, 1u, __float_as_uint(mn));
    return;
  }
  unsigned b4[4]; unsigned s4 = 0;
  #pragma unroll
  for (int j = 0; j < 4; ++j) {
    const int di = tid * 4 + j;
    const int bin = role ? di : (NBIN - 1 - di);
    b4[j] = ghist[c * 2 * NBIN + role * NBIN + bin];
    s4 += b4[j];
  }
  // inclusive scan of group sums over 256 threads
  unsigned x = s4;
  const int lane = tid & 63, wid = tid >> 6;
  #pragma unroll
  for (int d = 1; d < 64; d <<= 1) {
    const unsigned t = (unsigned)__shfl_up((int)x, d, 64);
    if (lane >= d) x += t;
  }
  if (lane == 63) wsum[wid] = x;
  __syncthreads();
  unsigned off = 0;
  #pragma unroll
  for (int w = 0; w < 4; ++w) if (w < wid) off += wsum[w];
  const unsigned gcum = x + off;
  const unsigned gprev = gcum - s4;
  if (gcum >= KSEL && gprev < KSEL) {
    unsigned run = gprev; int Tdi = tid * 4; unsigned strict = gprev;
    #pragma unroll
    for (int j = 0; j < 4; ++j) {
      if (run + b4[j] >= KSEL) { Tdi = tid * 4 + j; strict = run; break; }
      run += b4[j];
    }
    const int T = role ? Tdi : (NBIN - 1 - Tdi);
    trec[c * 2 + role] = make_uint4((unsigned)T, strict, 0u, 0u);
  }
}

// ------------------------------------------------- strict sums + boundary compaction
__global__ __launch_bounds__(256) void k_finalsum(const float* __restrict__ dist,
                                                  const int* __restrict__ y,
                                                  const unsigned* __restrict__ stats,
                                                  const uint4* __restrict__ trec,
                                                  float* __restrict__ ssum,
                                                  int* __restrict__ bcnt,
                                                  float* __restrict__ bbuf) {
  __shared__ float red[2][4];
  const int tid = threadIdx.x;
  const int c = blockIdx.x >> 4;
  const int n0 = (blockIdx.x & 15) * 4096;
  const uint4 rp = trec[c * 2 + 0];
  const uint4 rn = trec[c * 2 + 1];
  const float mnp = __uint_as_float(stats[c * 4 + 0]);
  const float mxp = __uint_as_float(stats[c * 4 + 1]);
  const float mnn = __uint_as_float(stats[c * 4 + 2]);
  const float mxn = __uint_as_float(stats[c * 4 + 3]);
  const float scp = (mxp > mnp) ? (float)NBIN / (mxp - mnp) : 0.f;
  const float scn = (mxn > mnn) ? (float)NBIN / (mxn - mnn) : 0.f;
  const int Tp = (int)rp.x, Tn = (int)rn.x;
  const bool dop = rp.z != 0u, don = rn.z != 0u;
  const float4* __restrict__ row4 = (const float4*)(dist + (size_t)c * N_SAMP + n0);
  const int4* __restrict__ y4 = (const int4*)(y + n0);
  float sp = 0.f, sn = 0.f;
  #pragma unroll
  for (int i = 0; i < 4; ++i) {
    const int idx = i * 256 + tid;
    const float4 v = row4[idx];
    const int4 yy = y4[idx];
    const float vv[4] = {v.x, v.y, v.z, v.w};
    const int ys[4] = {yy.x, yy.y, yy.z, yy.w};
    #pragma unroll
    for (int j = 0; j < 4; ++j) {
      const float v1 = vv[j];
      if (ys[j] == c) {
        if (!dop) {
          const int b = binOf(v1, mnp, scp);
          if (b > Tp) sp += v1;
          else if (b == Tp) {
            const int p = atomicAdd(&bcnt[c * 2 + 0], 1);
            if (p < BCAP) bbuf[(c * 2 + 0) * BCAP + p] = v1;
          }
        }
      } else {
        if (!don) {
          const int b = binOf(v1, mnn, scn);
          if (b < Tn) sn += v1;
          else if (b == Tn) {
            const int p = atomicAdd(&bcnt[c * 2 + 1], 1);
            if (p < BCAP) bbuf[(c * 2 + 1) * BCAP + p] = v1;
          }
        }
      }
    }
  }
  sp = wredAddF(sp); sn = wredAddF(sn);
  const int wid = tid >> 6;
  if ((tid & 63) == 0) { red[0][wid] = sp; red[1][wid] = sn; }
  __syncthreads();
  if (tid == 0) {
    float tp = red[0][0] + red[0][1] + red[0][2] + red[0][3];
    float tn = red[1][0] + red[1][1] + red[1][2] + red[1][3];
    if (tp != 0.f) atomicAdd(&ssum[c * 2 + 0], tp);
    if (tn != 0.f) atomicAdd(&ssum[c * 2 + 1], tn);
  }
}

// ------------------------------------------------- exact boundary resolve
// grid 128: c = bx>>1, role = bx&1. Sort <=256 boundary values, take needed extremes.
__global__ __launch_bounds__(256) void k_final(const uint4* __restrict__ trec,
                                               const float* __restrict__ ssum,
                                               const int* __restrict__ bcnt,
                                               const float* __restrict__ bbuf,
                                               float* __restrict__ means) {
  __shared__ float s[256];
  __shared__ float red[4];
  const int tid = threadIdx.x;
  const int c = blockIdx.x >> 1;
  const int role = blockIdx.x & 1;
  const uint4 r = trec[c * 2 + role];
  if (r.z != 0u) {  // degenerate: all values equal
    if (tid == 0) means[role * 64 + c] = __uint_as_float(r.w);
    return;
  }
  int cnt = bcnt[c * 2 + role];
  cnt = cnt < BCAP ? cnt : BCAP;
  int need = KSEL - (int)r.y;
  need = need < cnt ? need : cnt;
  const float pad = role ? __uint_as_float(0x7F800000u) : __uint_as_float(0xFF800000u); // +inf / -inf
  s[tid] = (tid < cnt) ? bbuf[(c * 2 + role) * BCAP + tid] : pad;
  __syncthreads();
  // bitonic ascending sort of 256
  for (int k = 2; k <= 256; k <<= 1) {
    for (int j = k >> 1; j > 0; j >>= 1) {
      const int ixj = tid ^ j;
      const float a = s[tid];
      const float b = s[ixj];
      __syncthreads();
      if (ixj > tid) {
        const bool asc = ((tid & k) == 0);
        if ((a > b) == asc) { s[tid] = b; s[ixj] = a; }
      }
      __syncthreads();
    }
  }
  // neg: smallest `need` -> [0, need); pos: largest `need` -> [256-need, 256)
  float v = 0.f;
  if (role) { if (tid < need) v = s[tid]; }
  else      { if (tid >= 256 - need) v = s[tid]; }
  v = wredAddF(v);
  if ((tid & 63) == 0) red[tid >> 6] = v;
  __syncthreads();
  if (tid == 0) {
    const float total = ssum[c * 2 + role] + red[0] + red[1] + red[2] + red[3];
    means[role * 64 + c] = total * (1.0f / (float)KSEL);
  }
}

// ------------------------------------------------- final loss
__global__ __launch_bounds__(64) void k_loss(const float* __restrict__ means, float* __restrict__ out) {
  const int c = threadIdx.x;
  float pc = fmaxf(1.0f + means[c] - means[64 + c], 0.0f);
  #pragma unroll
  for (int o = 32; o; o >>= 1) pc += __shfl_down(pc, o, 64);
  if (c == 0) out[0] = pc * (1.0f / 4096.0f);
}

// ----------------------------------------------------------------------
extern "C" void kernel_launch(void* const* d_in, const int* in_sizes, int n_in,
                              void* d_out, int out_size, void* d_ws, size_t ws_size,
                              hipStream_t stream) {
  const float* x = (const float*)d_in[0];
  const int* y = (const int*)d_in[1];
  float* out = (float*)d_out;
  char* w = (char*)d_ws;
  int* counts      = (int*)(w + OFF_COUNTS);
  float* csum      = (float*)(w + OFF_CSUM);
  float* centers   = (float*)(w + OFF_CENTERS);
  float* c2        = (float*)(w + OFF_C2);
  float* means     = (float*)(w + OFF_MEANS);
  float* dist      = (float*)(w + OFF_DIST);
  unsigned* stats  = (unsigned*)(w + OFF_STATS);
  unsigned* ghist  = (unsigned*)(w + OFF_HIST);
  uint4* trec      = (uint4*)(w + OFF_THRESH);
  float* ssum      = (float*)(w + OFF_SSUM);
  int* bcnt        = (int*)(w + OFF_BCNT);
  float* bbuf      = (float*)(w + OFF_BBUF);

  hipLaunchKernelGGL(k_init, dim3(512), dim3(256), 0, stream, counts, csum, stats, ghist, ssum, bcnt);
  hipLaunchKernelGGL(k_class_sums, dim3(1024), dim3(256), 0, stream, x, y, csum, counts);
  hipLaunchKernelGGL(k_centers, dim3(64), dim3(64), 0, stream, csum, counts, centers, c2);
  hipLaunchKernelGGL(k_dist, dim3(N_SAMP / TSAMP), dim3(256), 0, stream, x, centers, c2, dist);
  hipLaunchKernelGGL(k_stats, dim3(1024), dim3(256), 0, stream, dist, y, stats);
  hipLaunchKernelGGL(k_hist, dim3(1024), dim3(256), 0, stream, dist, y, stats, ghist);
  hipLaunchKernelGGL(k_thresh, dim3(128), dim3(256), 0, stream, ghist, stats, trec);
  hipLaunchKernelGGL(k_finalsum, dim3(1024), dim3(256), 0, stream, dist, y, stats, trec, ssum, bcnt, bbuf);
  hipLaunchKernelGGL(k_final, dim3(128), dim3(256), 0, stream, trec, ssum, bcnt, bbuf, means);
  hipLaunchKernelGGL(k_loss, dim3(1), dim3(64), 0, stream, means, out);
}

// Round 3
// 177.383 us; speedup vs baseline: 2.5754x; 1.5298x over previous
//
#include <hip/hip_runtime.h>
#include <math.h>

#define N_SAMP 65536
#define DIM    512
#define NCLS   64
#define KSEL   64
#define NBIN   1024
#define BCAP   256

// workspace layout (bytes)
#define OFF_COUNTS   0u           // 64 i32
#define OFF_CSUM     256u         // 64*512 f32
#define OFF_CENTERS  131328u      // cenT: 512*64 f32 (k-major, class-minor)
#define OFF_C2       262400u      // 64 f32
#define OFF_MEANS    262656u      // 128 f32 (pos[0..63], neg[64..127])
#define OFF_DIST     263168u      // 64*65536 f32  -> ends 17040384
#define OFF_STATS    17040384u    // 64*4 u32 {pmin,pmax,nmin,nmax} (float bits, dist>=0)
#define OFF_HIST     17041408u    // 64*2*1024 u32
#define OFF_THRESH   17565696u    // 128 * uint4 {T, strict_cnt, done, mean_bits}
#define OFF_SSUM     17569792u    // 128 f32 strict sums
#define OFF_BCNT     17570304u    // 128 i32 boundary counters
#define OFF_BBUF     17570816u    // 128 * 256 f32 boundary values

// ---------------------------------------------------------------- init
__global__ __launch_bounds__(256) void k_init(int* __restrict__ counts,
                                              float* __restrict__ csum,
                                              unsigned* __restrict__ stats,
                                              unsigned* __restrict__ ghist,
                                              float* __restrict__ ssum,
                                              int* __restrict__ bcnt) {
  const int i = blockIdx.x * 256 + threadIdx.x;
  const int stride = gridDim.x * 256;
  if (i < NCLS) counts[i] = 0;
  for (int j = i; j < NCLS * DIM; j += stride) csum[j] = 0.f;
  for (int j = i; j < NCLS * 4; j += stride) stats[j] = (j & 1) ? 0u : 0xFFFFFFFFu;
  for (int j = i; j < NCLS * 2 * NBIN; j += stride) ghist[j] = 0u;
  for (int j = i; j < 128; j += stride) { ssum[j] = 0.f; bcnt[j] = 0; }
}

// ------------------------------------------------- class partial sums
__global__ __launch_bounds__(256) void k_class_sums(const float* __restrict__ x,
                                                    const int* __restrict__ y,
                                                    float* __restrict__ csum,
                                                    int* __restrict__ counts) {
  __shared__ int list[4096];
  __shared__ int lcnt;
  const int c  = blockIdx.x >> 4;
  const int r0 = (blockIdx.x & 15) * 4096;
  const int tid = threadIdx.x;
  if (tid == 0) lcnt = 0;
  __syncthreads();
  for (int i = tid; i < 4096; i += 256) {
    if (y[r0 + i] == c) { int p = atomicAdd(&lcnt, 1); list[p] = r0 + i; }
  }
  __syncthreads();
  const int n = lcnt;
  const int dbase = (tid >> 6) * 128 + (tid & 63) * 2;
  float a0 = 0.f, a1 = 0.f, b0 = 0.f, b1 = 0.f;
  int i = 0;
  for (; i + 2 <= n; i += 2) {
    const float* p0 = x + (size_t)list[i] * DIM + dbase;
    const float* p1 = x + (size_t)list[i + 1] * DIM + dbase;
    a0 += p0[0]; a1 += p0[1];
    b0 += p1[0]; b1 += p1[1];
  }
  if (i < n) { const float* p0 = x + (size_t)list[i] * DIM + dbase; a0 += p0[0]; a1 += p0[1]; }
  a0 += b0; a1 += b1;
  atomicAdd(&csum[c * DIM + dbase], a0);
  atomicAdd(&csum[c * DIM + dbase + 1], a1);
  if (tid == 0) atomicAdd(&counts[c], n);
}

// ------------------------------------------------- finalize centers (transposed) + c2
__global__ __launch_bounds__(64) void k_centers(const float* __restrict__ csum,
                                                const int* __restrict__ counts,
                                                float* __restrict__ cenT,
                                                float* __restrict__ c2) {
  const int c = blockIdx.x, l = threadIdx.x;
  const float inv = 1.0f / (float)counts[c];
  float ss = 0.f;
  #pragma unroll
  for (int j = 0; j < 8; ++j) {
    int d = j * 64 + l;
    float v = csum[c * DIM + d] * inv;
    cenT[d * NCLS + c] = v;       // [k][class]
    ss += v * v;
  }
  #pragma unroll
  for (int o = 32; o; o >>= 1) ss += __shfl_down(ss, o, 64);
  if (l == 0) c2[c] = ss;
}

// ------------------------------------------------- distances [C][N]
// Block: 64 classes x 128 samples. 256 threads: cg=tid>>4 (4 classes: c0=cg*4),
// sg=tid&15 (8 samples: sBase=sg*8). Register tile acc[8 samp][4 cls], K-unroll 4.
#define TSAMP 128
#define KSTEP 64
#define XSTR  68
__global__ __launch_bounds__(256, 3) void k_dist(const float* __restrict__ x,
                                                 const float* __restrict__ cenT,
                                                 const float* __restrict__ c2,
                                                 float* __restrict__ dist) {
  __shared__ float xs[TSAMP * XSTR];      // 34816 B, k XOR-swizzled
  __shared__ float cs[KSTEP * NCLS];      // 16384 B, [k][class]
  __shared__ float x2s[TSAMP];
  __shared__ float c2s[NCLS];

  const int tid = threadIdx.x;
  const int s0 = blockIdx.x * TSAMP;
  const int cg = tid >> 4;
  const int sg = tid & 15;
  const int c0 = cg * 4;
  const int sBase = sg * 8;
  const int swzT = (sg & 7) << 2;         // read-side swizzle for this thread's samples

  if (tid < TSAMP) x2s[tid] = 0.f;
  if (tid < NCLS) c2s[tid] = c2[tid];

  float acc[8][4];
  #pragma unroll
  for (int i = 0; i < 8; ++i)
    #pragma unroll
    for (int j = 0; j < 4; ++j) acc[i][j] = 0.f;

  for (int kk = 0; kk < DIM; kk += KSTEP) {
    __syncthreads();
    // stage centers tile: contiguous 16KB from cenT
    {
      const float* gsrc = cenT + (size_t)kk * NCLS;
      #pragma unroll
      for (int r = 0; r < 4; ++r) {
        const int idx = tid + r * 256;
        const float4 v = *reinterpret_cast<const float4*>(gsrc + idx * 4);
        *reinterpret_cast<float4*>(&cs[idx * 4]) = v;
      }
    }
    // stage x tile (swizzled) + fused x^2 partial
    #pragma unroll
    for (int i = 0; i < 8; ++i) {
      const int idx = tid + i * 256;
      const int row = idx >> 4, c4 = idx & 15;
      const float4 v = *reinterpret_cast<const float4*>(x + (size_t)(s0 + row) * DIM + kk + c4 * 4);
      const int swz = ((row >> 3) & 7) << 2;
      *reinterpret_cast<float4*>(&xs[row * XSTR + ((c4 * 4) ^ swz)]) = v;
      float s2 = v.x * v.x + v.y * v.y + v.z * v.z + v.w * v.w;
      s2 += __shfl_xor(s2, 1, 64);
      s2 += __shfl_xor(s2, 2, 64);
      s2 += __shfl_xor(s2, 4, 64);
      s2 += __shfl_xor(s2, 8, 64);
      if ((tid & 15) == 0) atomicAdd(&x2s[row], s2);
    }
    __syncthreads();

    #pragma unroll
    for (int k4 = 0; k4 < KSTEP / 4; ++k4) {
      const int kq = k4 * 4;
      float4 cf[4];
      #pragma unroll
      for (int j = 0; j < 4; ++j)
        cf[j] = *reinterpret_cast<const float4*>(&cs[(kq + j) * NCLS + c0]);
      float4 xf[8];
      #pragma unroll
      for (int i = 0; i < 8; ++i)
        xf[i] = *reinterpret_cast<const float4*>(&xs[(sBase + i) * XSTR + (kq ^ swzT)]);
      #pragma unroll
      for (int i = 0; i < 8; ++i) {
        #pragma unroll
        for (int j = 0; j < 4; ++j) acc[i][j] = fmaf(xf[i].x, cf[0].x, acc[i][j]);
        // expand per k-sub with matching class lanes:
        acc[i][0] = fmaf(xf[i].y, cf[1].x, acc[i][0]);
        acc[i][1] = fmaf(xf[i].y, cf[1].y, acc[i][1]);
        acc[i][2] = fmaf(xf[i].y, cf[1].z, acc[i][2]);
        acc[i][3] = fmaf(xf[i].y, cf[1].w, acc[i][3]);
        acc[i][0] = fmaf(xf[i].z, cf[2].x, acc[i][0]);
        acc[i][1] = fmaf(xf[i].z, cf[2].y, acc[i][1]);
        acc[i][2] = fmaf(xf[i].z, cf[2].z, acc[i][2]);
        acc[i][3] = fmaf(xf[i].z, cf[2].w, acc[i][3]);
        acc[i][0] = fmaf(xf[i].w, cf[3].x, acc[i][0]);
        acc[i][1] = fmaf(xf[i].w, cf[3].y, acc[i][1]);
        acc[i][2] = fmaf(xf[i].w, cf[3].z, acc[i][2]);
        acc[i][3] = fmaf(xf[i].w, cf[3].w, acc[i][3]);
      }
    }
  }
  // fix the first k-sub (cf[0]) lanes: above first line used cf[0].x for all j — correct it by
  // construction instead: recompute is impossible; so we must NOT have merged. (See note.)
  __syncthreads();

  float x2v[8];
  #pragma unroll
  for (int i = 0; i < 8; ++i) x2v[i] = x2s[sBase + i];

  #pragma unroll
  for (int j = 0; j < 4; ++j) {
    const float cc2 = c2s[c0 + j];
    float4 o0, o1;
    o0.x = sqrtf(fmaxf(cc2 + x2v[0] - 2.0f * acc[0][j], 1e-12f));
    o0.y = sqrtf(fmaxf(cc2 + x2v[1] - 2.0f * acc[1][j], 1e-12f));
    o0.z = sqrtf(fmaxf(cc2 + x2v[2] - 2.0f * acc[2][j], 1e-12f));
    o0.w = sqrtf(fmaxf(cc2 + x2v[3] - 2.0f * acc[3][j], 1e-12f));
    o1.x = sqrtf(fmaxf(cc2 + x2v[4] - 2.0f * acc[4][j], 1e-12f));
    o1.y = sqrtf(fmaxf(cc2 + x2v[5] - 2.0f * acc[5][j], 1e-12f));
    o1.z = sqrtf(fmaxf(cc2 + x2v[6] - 2.0f * acc[6][j], 1e-12f));
    o1.w = sqrtf(fmaxf(cc2 + x2v[7] - 2.0f * acc[7][j], 1e-12f));
    float* dst = dist + (size_t)(c0 + j) * N_SAMP + s0 + sBase;
    *reinterpret_cast<float4*>(dst) = o0;
    *reinterpret_cast<float4*>(dst + 4) = o1;
  }
}

// NOTE on the FMA block above: the first unrolled line
//   for j: acc[i][j] = fmaf(xf[i].x, cf[0].x, acc[i][j])
// would be WRONG (uses cf[0].x for every class). It is overridden here with the
// correct per-class components by this macro-expanded corrected body:
// (The compiler never sees the wrong version because we define the kernel again
// below via a corrected copy. See k_dist_fixed.)

__global__ __launch_bounds__(256, 3) void k_dist_fixed(const float* __restrict__ x,
                                                       const float* __restrict__ cenT,
                                                       const float* __restrict__ c2,
                                                       float* __restrict__ dist) {
  __shared__ float xs[TSAMP * XSTR];
  __shared__ float cs[KSTEP * NCLS];
  __shared__ float x2s[TSAMP];
  __shared__ float c2s[NCLS];

  const int tid = threadIdx.x;
  const int s0 = blockIdx.x * TSAMP;
  const int cg = tid >> 4;
  const int sg = tid & 15;
  const int c0 = cg * 4;
  const int sBase = sg * 8;
  const int swzT = (sg & 7) << 2;

  if (tid < TSAMP) x2s[tid] = 0.f;
  if (tid < NCLS) c2s[tid] = c2[tid];

  float acc[8][4];
  #pragma unroll
  for (int i = 0; i < 8; ++i)
    #pragma unroll
    for (int j = 0; j < 4; ++j) acc[i][j] = 0.f;

  for (int kk = 0; kk < DIM; kk += KSTEP) {
    __syncthreads();
    {
      const float* gsrc = cenT + (size_t)kk * NCLS;
      #pragma unroll
      for (int r = 0; r < 4; ++r) {
        const int idx = tid + r * 256;
        const float4 v = *reinterpret_cast<const float4*>(gsrc + idx * 4);
        *reinterpret_cast<float4*>(&cs[idx * 4]) = v;
      }
    }
    #pragma unroll
    for (int i = 0; i < 8; ++i) {
      const int idx = tid + i * 256;
      const int row = idx >> 4, c4 = idx & 15;
      const float4 v = *reinterpret_cast<const float4*>(x + (size_t)(s0 + row) * DIM + kk + c4 * 4);
      const int swz = ((row >> 3) & 7) << 2;
      *reinterpret_cast<float4*>(&xs[row * XSTR + ((c4 * 4) ^ swz)]) = v;
      float s2 = v.x * v.x + v.y * v.y + v.z * v.z + v.w * v.w;
      s2 += __shfl_xor(s2, 1, 64);
      s2 += __shfl_xor(s2, 2, 64);
      s2 += __shfl_xor(s2, 4, 64);
      s2 += __shfl_xor(s2, 8, 64);
      if ((tid & 15) == 0) atomicAdd(&x2s[row], s2);
    }
    __syncthreads();

    #pragma unroll
    for (int k4 = 0; k4 < KSTEP / 4; ++k4) {
      const int kq = k4 * 4;
      float4 cf[4];
      #pragma unroll
      for (int j = 0; j < 4; ++j)
        cf[j] = *reinterpret_cast<const float4*>(&cs[(kq + j) * NCLS + c0]);
      float4 xf[8];
      #pragma unroll
      for (int i = 0; i < 8; ++i)
        xf[i] = *reinterpret_cast<const float4*>(&xs[(sBase + i) * XSTR + (kq ^ swzT)]);
      #pragma unroll
      for (int i = 0; i < 8; ++i) {
        acc[i][0] = fmaf(xf[i].x, cf[0].x, acc[i][0]);
        acc[i][1] = fmaf(xf[i].x, cf[0].y, acc[i][1]);
        acc[i][2] = fmaf(xf[i].x, cf[0].z, acc[i][2]);
        acc[i][3] = fmaf(xf[i].x, cf[0].w, acc[i][3]);
        acc[i][0] = fmaf(xf[i].y, cf[1].x, acc[i][0]);
        acc[i][1] = fmaf(xf[i].y, cf[1].y, acc[i][1]);
        acc[i][2] = fmaf(xf[i].y, cf[1].z, acc[i][2]);
        acc[i][3] = fmaf(xf[i].y, cf[1].w, acc[i][3]);
        acc[i][0] = fmaf(xf[i].z, cf[2].x, acc[i][0]);
        acc[i][1] = fmaf(xf[i].z, cf[2].y, acc[i][1]);
        acc[i][2] = fmaf(xf[i].z, cf[2].z, acc[i][2]);
        acc[i][3] = fmaf(xf[i].z, cf[2].w, acc[i][3]);
        acc[i][0] = fmaf(xf[i].w, cf[3].x, acc[i][0]);
        acc[i][1] = fmaf(xf[i].w, cf[3].y, acc[i][1]);
        acc[i][2] = fmaf(xf[i].w, cf[3].z, acc[i][2]);
        acc[i][3] = fmaf(xf[i].w, cf[3].w, acc[i][3]);
      }
    }
  }
  __syncthreads();

  float x2v[8];
  #pragma unroll
  for (int i = 0; i < 8; ++i) x2v[i] = x2s[sBase + i];

  #pragma unroll
  for (int j = 0; j < 4; ++j) {
    const float cc2 = c2s[c0 + j];
    float4 o0, o1;
    o0.x = sqrtf(fmaxf(cc2 + x2v[0] - 2.0f * acc[0][j], 1e-12f));
    o0.y = sqrtf(fmaxf(cc2 + x2v[1] - 2.0f * acc[1][j], 1e-12f));
    o0.z = sqrtf(fmaxf(cc2 + x2v[2] - 2.0f * acc[2][j], 1e-12f));
    o0.w = sqrtf(fmaxf(cc2 + x2v[3] - 2.0f * acc[3][j], 1e-12f));
    o1.x = sqrtf(fmaxf(cc2 + x2v[4] - 2.0f * acc[4][j], 1e-12f));
    o1.y = sqrtf(fmaxf(cc2 + x2v[5] - 2.0f * acc[5][j], 1e-12f));
    o1.z = sqrtf(fmaxf(cc2 + x2v[6] - 2.0f * acc[6][j], 1e-12f));
    o1.w = sqrtf(fmaxf(cc2 + x2v[7] - 2.0f * acc[7][j], 1e-12f));
    float* dst = dist + (size_t)(c0 + j) * N_SAMP + s0 + sBase;
    *reinterpret_cast<float4*>(dst) = o0;
    *reinterpret_cast<float4*>(dst + 4) = o1;
  }
}

// ------------------------------------------------- helpers
__device__ __forceinline__ unsigned wredMinU(unsigned v) {
  #pragma unroll
  for (int o = 32; o; o >>= 1) { unsigned t = (unsigned)__shfl_xor((int)v, o, 64); v = v < t ? v : t; }
  return v;
}
__device__ __forceinline__ unsigned wredMaxU(unsigned v) {
  #pragma unroll
  for (int o = 32; o; o >>= 1) { unsigned t = (unsigned)__shfl_xor((int)v, o, 64); v = v > t ? v : t; }
  return v;
}
__device__ __forceinline__ float wredAddF(float v) {
  #pragma unroll
  for (int o = 32; o; o >>= 1) v += __shfl_xor(v, o, 64);
  return v;
}
__device__ __forceinline__ int binOf(float v, float mn, float scale) {
  int b = (int)((v - mn) * scale);
  b = b < NBIN - 1 ? b : NBIN - 1;
  return b > 0 ? b : 0;
}

// ------------------------------------------------- per-(class,role) min/max
__global__ __launch_bounds__(256) void k_stats(const float* __restrict__ dist,
                                               const int* __restrict__ y,
                                               unsigned* __restrict__ stats) {
  __shared__ unsigned red[4][4];
  const int tid = threadIdx.x;
  const int c = blockIdx.x >> 4;
  const int n0 = (blockIdx.x & 15) * 4096;
  const float4* __restrict__ row4 = (const float4*)(dist + (size_t)c * N_SAMP + n0);
  const int4* __restrict__ y4 = (const int4*)(y + n0);
  unsigned pmin = 0xFFFFFFFFu, pmax = 0u, nmin = 0xFFFFFFFFu, nmax = 0u;
  #pragma unroll
  for (int i = 0; i < 4; ++i) {
    const int idx = i * 256 + tid;
    const float4 v = row4[idx];
    const int4 yy = y4[idx];
    const float vv[4] = {v.x, v.y, v.z, v.w};
    const int ys[4] = {yy.x, yy.y, yy.z, yy.w};
    #pragma unroll
    for (int j = 0; j < 4; ++j) {
      const unsigned b = __float_as_uint(vv[j]);
      if (ys[j] == c) { pmin = b < pmin ? b : pmin; pmax = b > pmax ? b : pmax; }
      else            { nmin = b < nmin ? b : nmin; nmax = b > nmax ? b : nmax; }
    }
  }
  pmin = wredMinU(pmin); pmax = wredMaxU(pmax);
  nmin = wredMinU(nmin); nmax = wredMaxU(nmax);
  const int wid = tid >> 6;
  if ((tid & 63) == 0) { red[wid][0] = pmin; red[wid][1] = pmax; red[wid][2] = nmin; red[wid][3] = nmax; }
  __syncthreads();
  if (tid == 0) {
    unsigned a0 = red[0][0], a1 = red[0][1], a2 = red[0][2], a3 = red[0][3];
    #pragma unroll
    for (int w = 1; w < 4; ++w) {
      a0 = red[w][0] < a0 ? red[w][0] : a0;
      a1 = red[w][1] > a1 ? red[w][1] : a1;
      a2 = red[w][2] < a2 ? red[w][2] : a2;
      a3 = red[w][3] > a3 ? red[w][3] : a3;
    }
    atomicMin(&stats[c * 4 + 0], a0);
    atomicMax(&stats[c * 4 + 1], a1);
    atomicMin(&stats[c * 4 + 2], a2);
    atomicMax(&stats[c * 4 + 3], a3);
  }
}

// ------------------------------------------------- adaptive histograms
__global__ __launch_bounds__(256) void k_hist(const float* __restrict__ dist,
                                              const int* __restrict__ y,
                                              const unsigned* __restrict__ stats,
                                              unsigned* __restrict__ ghist) {
  __shared__ unsigned lh[2 * NBIN];
  const int tid = threadIdx.x;
  const int c = blockIdx.x >> 4;
  const int n0 = (blockIdx.x & 15) * 4096;
  for (int i = tid; i < 2 * NBIN; i += 256) lh[i] = 0u;
  const float mnp = __uint_as_float(stats[c * 4 + 0]);
  const float mxp = __uint_as_float(stats[c * 4 + 1]);
  const float mnn = __uint_as_float(stats[c * 4 + 2]);
  const float mxn = __uint_as_float(stats[c * 4 + 3]);
  const float scp = (mxp > mnp) ? (float)NBIN / (mxp - mnp) : 0.f;
  const float scn = (mxn > mnn) ? (float)NBIN / (mxn - mnn) : 0.f;
  __syncthreads();
  const float4* __restrict__ row4 = (const float4*)(dist + (size_t)c * N_SAMP + n0);
  const int4* __restrict__ y4 = (const int4*)(y + n0);
  #pragma unroll
  for (int i = 0; i < 4; ++i) {
    const int idx = i * 256 + tid;
    const float4 v = row4[idx];
    const int4 yy = y4[idx];
    const float vv[4] = {v.x, v.y, v.z, v.w};
    const int ys[4] = {yy.x, yy.y, yy.z, yy.w};
    #pragma unroll
    for (int j = 0; j < 4; ++j) {
      if (ys[j] == c) atomicAdd(&lh[binOf(vv[j], mnp, scp)], 1u);
      else            atomicAdd(&lh[NBIN + binOf(vv[j], mnn, scn)], 1u);
    }
  }
  __syncthreads();
  for (int i = tid; i < 2 * NBIN; i += 256) {
    const unsigned v = lh[i];
    if (v) atomicAdd(&ghist[c * 2 * NBIN + i], v);
  }
}

// ------------------------------------------------- find boundary bin per (c,role)
__global__ __launch_bounds__(256) void k_thresh(const unsigned* __restrict__ ghist,
                                                const unsigned* __restrict__ stats,
                                                uint4* __restrict__ trec) {
  __shared__ unsigned wsum[4];
  const int tid = threadIdx.x;
  const int c = blockIdx.x >> 1;
  const int role = blockIdx.x & 1;
  const float mn = __uint_as_float(stats[c * 4 + role * 2]);
  const float mx = __uint_as_float(stats[c * 4 + role * 2 + 1]);
  if (!(mx > mn)) {
    if (tid == 0) trec[c * 2 + role] = make_uint4(0u, 0u, 1u, __float_as_uint(mn));
    return;
  }
  unsigned b4[4]; unsigned s4 = 0;
  #pragma unroll
  for (int j = 0; j < 4; ++j) {
    const int di = tid * 4 + j;
    const int bin = role ? di : (NBIN - 1 - di);
    b4[j] = ghist[c * 2 * NBIN + role * NBIN + bin];
    s4 += b4[j];
  }
  unsigned xs = s4;
  const int lane = tid & 63, wid = tid >> 6;
  #pragma unroll
  for (int d = 1; d < 64; d <<= 1) {
    const unsigned t = (unsigned)__shfl_up((int)xs, d, 64);
    if (lane >= d) xs += t;
  }
  if (lane == 63) wsum[wid] = xs;
  __syncthreads();
  unsigned off = 0;
  #pragma unroll
  for (int w = 0; w < 4; ++w) if (w < wid) off += wsum[w];
  const unsigned gcum = xs + off;
  const unsigned gprev = gcum - s4;
  if (gcum >= KSEL && gprev < KSEL) {
    unsigned run = gprev; int Tdi = tid * 4; unsigned strict = gprev;
    #pragma unroll
    for (int j = 0; j < 4; ++j) {
      if (run + b4[j] >= KSEL) { Tdi = tid * 4 + j; strict = run; break; }
      run += b4[j];
    }
    const int T = role ? Tdi : (NBIN - 1 - Tdi);
    trec[c * 2 + role] = make_uint4((unsigned)T, strict, 0u, 0u);
  }
}

// ------------------------------------------------- strict sums + boundary compaction
__global__ __launch_bounds__(256) void k_finalsum(const float* __restrict__ dist,
                                                  const int* __restrict__ y,
                                                  const unsigned* __restrict__ stats,
                                                  const uint4* __restrict__ trec,
                                                  float* __restrict__ ssum,
                                                  int* __restrict__ bcnt,
                                                  float* __restrict__ bbuf) {
  __shared__ float red[2][4];
  const int tid = threadIdx.x;
  const int c = blockIdx.x >> 4;
  const int n0 = (blockIdx.x & 15) * 4096;
  const uint4 rp = trec[c * 2 + 0];
  const uint4 rn = trec[c * 2 + 1];
  const float mnp = __uint_as_float(stats[c * 4 + 0]);
  const float mxp = __uint_as_float(stats[c * 4 + 1]);
  const float mnn = __uint_as_float(stats[c * 4 + 2]);
  const float mxn = __uint_as_float(stats[c * 4 + 3]);
  const float scp = (mxp > mnp) ? (float)NBIN / (mxp - mnp) : 0.f;
  const float scn = (mxn > mnn) ? (float)NBIN / (mxn - mnn) : 0.f;
  const int Tp = (int)rp.x, Tn = (int)rn.x;
  const bool dop = rp.z != 0u, don = rn.z != 0u;
  const float4* __restrict__ row4 = (const float4*)(dist + (size_t)c * N_SAMP + n0);
  const int4* __restrict__ y4 = (const int4*)(y + n0);
  float sp = 0.f, sn = 0.f;
  #pragma unroll
  for (int i = 0; i < 4; ++i) {
    const int idx = i * 256 + tid;
    const float4 v = row4[idx];
    const int4 yy = y4[idx];
    const float vv[4] = {v.x, v.y, v.z, v.w};
    const int ys[4] = {yy.x, yy.y, yy.z, yy.w};
    #pragma unroll
    for (int j = 0; j < 4; ++j) {
      const float v1 = vv[j];
      if (ys[j] == c) {
        if (!dop) {
          const int b = binOf(v1, mnp, scp);
          if (b > Tp) sp += v1;
          else if (b == Tp) {
            const int p = atomicAdd(&bcnt[c * 2 + 0], 1);
            if (p < BCAP) bbuf[(c * 2 + 0) * BCAP + p] = v1;
          }
        }
      } else {
        if (!don) {
          const int b = binOf(v1, mnn, scn);
          if (b < Tn) sn += v1;
          else if (b == Tn) {
            const int p = atomicAdd(&bcnt[c * 2 + 1], 1);
            if (p < BCAP) bbuf[(c * 2 + 1) * BCAP + p] = v1;
          }
        }
      }
    }
  }
  sp = wredAddF(sp); sn = wredAddF(sn);
  const int wid = tid >> 6;
  if ((tid & 63) == 0) { red[0][wid] = sp; red[1][wid] = sn; }
  __syncthreads();
  if (tid == 0) {
    float tp = red[0][0] + red[0][1] + red[0][2] + red[0][3];
    float tn = red[1][0] + red[1][1] + red[1][2] + red[1][3];
    if (tp != 0.f) atomicAdd(&ssum[c * 2 + 0], tp);
    if (tn != 0.f) atomicAdd(&ssum[c * 2 + 1], tn);
  }
}

// ------------------------------------------------- exact boundary resolve
__global__ __launch_bounds__(256) void k_final(const uint4* __restrict__ trec,
                                               const float* __restrict__ ssum,
                                               const int* __restrict__ bcnt,
                                               const float* __restrict__ bbuf,
                                               float* __restrict__ means) {
  __shared__ float s[256];
  __shared__ float red[4];
  const int tid = threadIdx.x;
  const int c = blockIdx.x >> 1;
  const int role = blockIdx.x & 1;
  const uint4 r = trec[c * 2 + role];
  if (r.z != 0u) {
    if (tid == 0) means[role * 64 + c] = __uint_as_float(r.w);
    return;
  }
  int cnt = bcnt[c * 2 + role];
  cnt = cnt < BCAP ? cnt : BCAP;
  int need = KSEL - (int)r.y;
  need = need < cnt ? need : cnt;
  const float pad = role ? __uint_as_float(0x7F800000u) : __uint_as_float(0xFF800000u);
  s[tid] = (tid < cnt) ? bbuf[(c * 2 + role) * BCAP + tid] : pad;
  __syncthreads();
  for (int k = 2; k <= 256; k <<= 1) {
    for (int j = k >> 1; j > 0; j >>= 1) {
      const int ixj = tid ^ j;
      const float a = s[tid];
      const float b = s[ixj];
      __syncthreads();
      if (ixj > tid) {
        const bool asc = ((tid & k) == 0);
        if ((a > b) == asc) { s[tid] = b; s[ixj] = a; }
      }
      __syncthreads();
    }
  }
  float v = 0.f;
  if (role) { if (tid < need) v = s[tid]; }
  else      { if (tid >= 256 - need) v = s[tid]; }
  v = wredAddF(v);
  if ((tid & 63) == 0) red[tid >> 6] = v;
  __syncthreads();
  if (tid == 0) {
    const float total = ssum[c * 2 + role] + red[0] + red[1] + red[2] + red[3];
    means[role * 64 + c] = total * (1.0f / (float)KSEL);
  }
}

// ------------------------------------------------- final loss
__global__ __launch_bounds__(64) void k_loss(const float* __restrict__ means, float* __restrict__ out) {
  const int c = threadIdx.x;
  float pc = fmaxf(1.0f + means[c] - means[64 + c], 0.0f);
  #pragma unroll
  for (int o = 32; o; o >>= 1) pc += __shfl_down(pc, o, 64);
  if (c == 0) out[0] = pc * (1.0f / 4096.0f);
}

// ----------------------------------------------------------------------
extern "C" void kernel_launch(void* const* d_in, const int* in_sizes, int n_in,
                              void* d_out, int out_size, void* d_ws, size_t ws_size,
                              hipStream_t stream) {
  const float* x = (const float*)d_in[0];
  const int* y = (const int*)d_in[1];
  float* out = (float*)d_out;
  char* w = (char*)d_ws;
  int* counts      = (int*)(w + OFF_COUNTS);
  float* csum      = (float*)(w + OFF_CSUM);
  float* cenT      = (float*)(w + OFF_CENTERS);
  float* c2        = (float*)(w + OFF_C2);
  float* means     = (float*)(w + OFF_MEANS);
  float* dist      = (float*)(w + OFF_DIST);
  unsigned* stats  = (unsigned*)(w + OFF_STATS);
  unsigned* ghist  = (unsigned*)(w + OFF_HIST);
  uint4* trec      = (uint4*)(w + OFF_THRESH);
  float* ssum      = (float*)(w + OFF_SSUM);
  int* bcnt        = (int*)(w + OFF_BCNT);
  float* bbuf      = (float*)(w + OFF_BBUF);

  hipLaunchKernelGGL(k_init, dim3(512), dim3(256), 0, stream, counts, csum, stats, ghist, ssum, bcnt);
  hipLaunchKernelGGL(k_class_sums, dim3(1024), dim3(256), 0, stream, x, y, csum, counts);
  hipLaunchKernelGGL(k_centers, dim3(64), dim3(64), 0, stream, csum, counts, cenT, c2);
  hipLaunchKernelGGL(k_dist_fixed, dim3(N_SAMP / TSAMP), dim3(256), 0, stream, x, cenT, c2, dist);
  hipLaunchKernelGGL(k_stats, dim3(1024), dim3(256), 0, stream, dist, y, stats);
  hipLaunchKernelGGL(k_hist, dim3(1024), dim3(256), 0, stream, dist, y, stats, ghist);
  hipLaunchKernelGGL(k_thresh, dim3(128), dim3(256), 0, stream, ghist, stats, trec);
  hipLaunchKernelGGL(k_finalsum, dim3(1024), dim3(256), 0, stream, dist, y, stats, trec, ssum, bcnt, bbuf);
  hipLaunchKernelGGL(k_final, dim3(128), dim3(256), 0, stream, trec, ssum, bcnt, bbuf, means);
  hipLaunchKernelGGL(k_loss, dim3(1), dim3(64), 0, stream, means, out);
}

// Round 4
// 100.842 us; speedup vs baseline: 4.5302x; 1.7590x over previous
//
#include <hip/hip_runtime.h>
#include <math.h>

#define N_SAMP 65536
#define DIM    512
#define NCLS   64
#define KSEL   64
#define NBIN   1024
#define BCAP   256

// workspace layout (bytes)
#define OFF_COUNTS   0u           // 64 i32
#define OFF_CSUM     256u         // 64*512 f32
#define OFF_CENTERS  131328u      // cenb: 64*512 bf16 (row-major)
#define OFF_C2       262400u      // 64 f32
#define OFF_MEANS    262656u      // 128 f32 (pos[0..63], neg[64..127])
#define OFF_DIST     263168u      // 64*65536 f32  -> ends 17040384
#define OFF_STATS    17040384u    // 64*4 u32 {pmin,pmax,nmin,nmax} (float bits, dist>=0)
#define OFF_HIST     17041408u    // 64*2*1024 u32
#define OFF_THRESH   17565696u    // 128 * uint4 {T, strict_cnt, done, mean_bits}
#define OFF_SSUM     17569792u    // 128 f32 strict sums
#define OFF_BCNT     17570304u    // 128 i32 boundary counters
#define OFF_BBUF     17570816u    // 128 * 256 f32 boundary values

typedef __attribute__((ext_vector_type(8))) short bf16x8;
typedef __attribute__((ext_vector_type(4))) float f32x4;

__device__ __forceinline__ unsigned short f2bf_rne(float f) {
  const unsigned u = __float_as_uint(f);
  return (unsigned short)((u + 0x7FFFu + ((u >> 16) & 1u)) >> 16);
}

// ---------------------------------------------------------------- init
__global__ __launch_bounds__(256) void k_init(int* __restrict__ counts,
                                              float* __restrict__ csum,
                                              unsigned* __restrict__ stats,
                                              unsigned* __restrict__ ghist,
                                              float* __restrict__ ssum,
                                              int* __restrict__ bcnt) {
  const int i = blockIdx.x * 256 + threadIdx.x;
  const int stride = gridDim.x * 256;
  if (i < NCLS) counts[i] = 0;
  for (int j = i; j < NCLS * DIM; j += stride) csum[j] = 0.f;
  for (int j = i; j < NCLS * 4; j += stride) stats[j] = (j & 1) ? 0u : 0xFFFFFFFFu;
  for (int j = i; j < NCLS * 2 * NBIN; j += stride) ghist[j] = 0u;
  for (int j = i; j < 128; j += stride) { ssum[j] = 0.f; bcnt[j] = 0; }
}

// ------------------------------------------------- class partial sums
__global__ __launch_bounds__(256) void k_class_sums(const float* __restrict__ x,
                                                    const int* __restrict__ y,
                                                    float* __restrict__ csum,
                                                    int* __restrict__ counts) {
  __shared__ int list[4096];
  __shared__ int lcnt;
  const int c  = blockIdx.x >> 4;
  const int r0 = (blockIdx.x & 15) * 4096;
  const int tid = threadIdx.x;
  if (tid == 0) lcnt = 0;
  __syncthreads();
  for (int i = tid; i < 4096; i += 256) {
    if (y[r0 + i] == c) { int p = atomicAdd(&lcnt, 1); list[p] = r0 + i; }
  }
  __syncthreads();
  const int n = lcnt;
  const int dbase = (tid >> 6) * 128 + (tid & 63) * 2;
  float a0 = 0.f, a1 = 0.f, b0 = 0.f, b1 = 0.f;
  int i = 0;
  for (; i + 2 <= n; i += 2) {
    const float* p0 = x + (size_t)list[i] * DIM + dbase;
    const float* p1 = x + (size_t)list[i + 1] * DIM + dbase;
    a0 += p0[0]; a1 += p0[1];
    b0 += p1[0]; b1 += p1[1];
  }
  if (i < n) { const float* p0 = x + (size_t)list[i] * DIM + dbase; a0 += p0[0]; a1 += p0[1]; }
  a0 += b0; a1 += b1;
  atomicAdd(&csum[c * DIM + dbase], a0);
  atomicAdd(&csum[c * DIM + dbase + 1], a1);
  if (tid == 0) atomicAdd(&counts[c], n);
}

// ------------------------------------------------- finalize centers (bf16 row-major) + c2 (f32)
__global__ __launch_bounds__(64) void k_centers(const float* __restrict__ csum,
                                                const int* __restrict__ counts,
                                                unsigned short* __restrict__ cenb,
                                                float* __restrict__ c2) {
  const int c = blockIdx.x, l = threadIdx.x;
  const float inv = 1.0f / (float)counts[c];
  float ss = 0.f;
  #pragma unroll
  for (int j = 0; j < 8; ++j) {
    int d = j * 64 + l;
    float v = csum[c * DIM + d] * inv;
    cenb[c * DIM + d] = f2bf_rne(v);
    ss += v * v;
  }
  #pragma unroll
  for (int o = 32; o; o >>= 1) ss += __shfl_down(ss, o, 64);
  if (l == 0) c2[c] = ss;
}

// ------------------------------------------------- distances via bf16 MFMA
// 512 blocks x 512 threads (8 waves). Wave w: samples blk*128 + w*16 .. +15, all 64 classes.
// Centers staged once in LDS (padded stride 520 -> 2-way banks). x read fp32, cvt in-reg.
#define CSTR 520
__global__ __launch_bounds__(512, 4) void k_dist_mfma(const float* __restrict__ x,
                                                      const unsigned short* __restrict__ cenb,
                                                      const float* __restrict__ c2,
                                                      float* __restrict__ dist) {
  __shared__ unsigned short cenS[NCLS * CSTR];   // 66560 B
  __shared__ float c2s[NCLS];

  const int tid = threadIdx.x;
  const int wave = tid >> 6;
  const int lane = tid & 63;
  const int s0 = blockIdx.x * 128 + wave * 16;
  const int samp = s0 + (lane & 15);
  const int kg = lane >> 4;                      // k-group 0..3

  // stage centers: 4096 chunks of 8 bf16
  for (int q = tid; q < 4096; q += 512) {
    const int row = q >> 6, cc = q & 63;
    const uint4 v = *reinterpret_cast<const uint4*>(cenb + row * DIM + cc * 8);
    *reinterpret_cast<uint4*>(&cenS[row * CSTR + cc * 8]) = v;
  }
  if (tid < NCLS) c2s[tid] = c2[tid];
  __syncthreads();

  f32x4 acc[4] = {f32x4{0,0,0,0}, f32x4{0,0,0,0}, f32x4{0,0,0,0}, f32x4{0,0,0,0}};
  float x2 = 0.f;
  const float* __restrict__ xrow = x + (size_t)samp * DIM + kg * 8;
  const int arow = lane & 15;

  #pragma unroll 4
  for (int s = 0; s < 16; ++s) {
    const int k0 = s * 32;
    float xf[8];
    *reinterpret_cast<float4*>(&xf[0]) = *reinterpret_cast<const float4*>(xrow + k0);
    *reinterpret_cast<float4*>(&xf[4]) = *reinterpret_cast<const float4*>(xrow + k0 + 4);
    bf16x8 bfrag;
    #pragma unroll
    for (int j = 0; j < 8; ++j) {
      x2 = fmaf(xf[j], xf[j], x2);
      const unsigned u = __float_as_uint(xf[j]);
      bfrag[j] = (short)((u + 0x7FFFu + ((u >> 16) & 1u)) >> 16);
    }
    const int kidx = k0 + kg * 8;
    const bf16x8 a0 = *reinterpret_cast<const bf16x8*>(&cenS[(arow +  0) * CSTR + kidx]);
    const bf16x8 a1 = *reinterpret_cast<const bf16x8*>(&cenS[(arow + 16) * CSTR + kidx]);
    const bf16x8 a2 = *reinterpret_cast<const bf16x8*>(&cenS[(arow + 32) * CSTR + kidx]);
    const bf16x8 a3 = *reinterpret_cast<const bf16x8*>(&cenS[(arow + 48) * CSTR + kidx]);
    acc[0] = __builtin_amdgcn_mfma_f32_16x16x32_bf16(a0, bfrag, acc[0], 0, 0, 0);
    acc[1] = __builtin_amdgcn_mfma_f32_16x16x32_bf16(a1, bfrag, acc[1], 0, 0, 0);
    acc[2] = __builtin_amdgcn_mfma_f32_16x16x32_bf16(a2, bfrag, acc[2], 0, 0, 0);
    acc[3] = __builtin_amdgcn_mfma_f32_16x16x32_bf16(a3, bfrag, acc[3], 0, 0, 0);
  }

  // full x^2 for this lane's sample: sum the 4 k-groups
  x2 += __shfl_xor(x2, 16, 64);
  x2 += __shfl_xor(x2, 32, 64);

  const int col = s0 + (lane & 15);
  #pragma unroll
  for (int t = 0; t < 4; ++t) {
    #pragma unroll
    for (int r = 0; r < 4; ++r) {
      const int cls = t * 16 + (lane >> 4) * 4 + r;
      const float d2 = c2s[cls] + x2 - 2.0f * acc[t][r];
      dist[(size_t)cls * N_SAMP + col] = sqrtf(fmaxf(d2, 1e-12f));
    }
  }
}

// ------------------------------------------------- helpers
__device__ __forceinline__ unsigned wredMinU(unsigned v) {
  #pragma unroll
  for (int o = 32; o; o >>= 1) { unsigned t = (unsigned)__shfl_xor((int)v, o, 64); v = v < t ? v : t; }
  return v;
}
__device__ __forceinline__ unsigned wredMaxU(unsigned v) {
  #pragma unroll
  for (int o = 32; o; o >>= 1) { unsigned t = (unsigned)__shfl_xor((int)v, o, 64); v = v > t ? v : t; }
  return v;
}
__device__ __forceinline__ float wredAddF(float v) {
  #pragma unroll
  for (int o = 32; o; o >>= 1) v += __shfl_xor(v, o, 64);
  return v;
}
__device__ __forceinline__ int binOf(float v, float mn, float scale) {
  int b = (int)((v - mn) * scale);
  b = b < NBIN - 1 ? b : NBIN - 1;
  return b > 0 ? b : 0;
}

// ------------------------------------------------- per-(class,role) min/max
__global__ __launch_bounds__(256) void k_stats(const float* __restrict__ dist,
                                               const int* __restrict__ y,
                                               unsigned* __restrict__ stats) {
  __shared__ unsigned red[4][4];
  const int tid = threadIdx.x;
  const int c = blockIdx.x >> 4;
  const int n0 = (blockIdx.x & 15) * 4096;
  const float4* __restrict__ row4 = (const float4*)(dist + (size_t)c * N_SAMP + n0);
  const int4* __restrict__ y4 = (const int4*)(y + n0);
  unsigned pmin = 0xFFFFFFFFu, pmax = 0u, nmin = 0xFFFFFFFFu, nmax = 0u;
  #pragma unroll
  for (int i = 0; i < 4; ++i) {
    const int idx = i * 256 + tid;
    const float4 v = row4[idx];
    const int4 yy = y4[idx];
    const float vv[4] = {v.x, v.y, v.z, v.w};
    const int ys[4] = {yy.x, yy.y, yy.z, yy.w};
    #pragma unroll
    for (int j = 0; j < 4; ++j) {
      const unsigned b = __float_as_uint(vv[j]);
      if (ys[j] == c) { pmin = b < pmin ? b : pmin; pmax = b > pmax ? b : pmax; }
      else            { nmin = b < nmin ? b : nmin; nmax = b > nmax ? b : nmax; }
    }
  }
  pmin = wredMinU(pmin); pmax = wredMaxU(pmax);
  nmin = wredMinU(nmin); nmax = wredMaxU(nmax);
  const int wid = tid >> 6;
  if ((tid & 63) == 0) { red[wid][0] = pmin; red[wid][1] = pmax; red[wid][2] = nmin; red[wid][3] = nmax; }
  __syncthreads();
  if (tid == 0) {
    unsigned a0 = red[0][0], a1 = red[0][1], a2 = red[0][2], a3 = red[0][3];
    #pragma unroll
    for (int w = 1; w < 4; ++w) {
      a0 = red[w][0] < a0 ? red[w][0] : a0;
      a1 = red[w][1] > a1 ? red[w][1] : a1;
      a2 = red[w][2] < a2 ? red[w][2] : a2;
      a3 = red[w][3] > a3 ? red[w][3] : a3;
    }
    atomicMin(&stats[c * 4 + 0], a0);
    atomicMax(&stats[c * 4 + 1], a1);
    atomicMin(&stats[c * 4 + 2], a2);
    atomicMax(&stats[c * 4 + 3], a3);
  }
}

// ------------------------------------------------- adaptive histograms
__global__ __launch_bounds__(256) void k_hist(const float* __restrict__ dist,
                                              const int* __restrict__ y,
                                              const unsigned* __restrict__ stats,
                                              unsigned* __restrict__ ghist) {
  __shared__ unsigned lh[2 * NBIN];
  const int tid = threadIdx.x;
  const int c = blockIdx.x >> 4;
  const int n0 = (blockIdx.x & 15) * 4096;
  for (int i = tid; i < 2 * NBIN; i += 256) lh[i] = 0u;
  const float mnp = __uint_as_float(stats[c * 4 + 0]);
  const float mxp = __uint_as_float(stats[c * 4 + 1]);
  const float mnn = __uint_as_float(stats[c * 4 + 2]);
  const float mxn = __uint_as_float(stats[c * 4 + 3]);
  const float scp = (mxp > mnp) ? (float)NBIN / (mxp - mnp) : 0.f;
  const float scn = (mxn > mnn) ? (float)NBIN / (mxn - mnn) : 0.f;
  __syncthreads();
  const float4* __restrict__ row4 = (const float4*)(dist + (size_t)c * N_SAMP + n0);
  const int4* __restrict__ y4 = (const int4*)(y + n0);
  #pragma unroll
  for (int i = 0; i < 4; ++i) {
    const int idx = i * 256 + tid;
    const float4 v = row4[idx];
    const int4 yy = y4[idx];
    const float vv[4] = {v.x, v.y, v.z, v.w};
    const int ys[4] = {yy.x, yy.y, yy.z, yy.w};
    #pragma unroll
    for (int j = 0; j < 4; ++j) {
      if (ys[j] == c) atomicAdd(&lh[binOf(vv[j], mnp, scp)], 1u);
      else            atomicAdd(&lh[NBIN + binOf(vv[j], mnn, scn)], 1u);
    }
  }
  __syncthreads();
  for (int i = tid; i < 2 * NBIN; i += 256) {
    const unsigned v = lh[i];
    if (v) atomicAdd(&ghist[c * 2 * NBIN + i], v);
  }
}

// ------------------------------------------------- find boundary bin per (c,role)
__global__ __launch_bounds__(256) void k_thresh(const unsigned* __restrict__ ghist,
                                                const unsigned* __restrict__ stats,
                                                uint4* __restrict__ trec) {
  __shared__ unsigned wsum[4];
  const int tid = threadIdx.x;
  const int c = blockIdx.x >> 1;
  const int role = blockIdx.x & 1;
  const float mn = __uint_as_float(stats[c * 4 + role * 2]);
  const float mx = __uint_as_float(stats[c * 4 + role * 2 + 1]);
  if (!(mx > mn)) {
    if (tid == 0) trec[c * 2 + role] = make_uint4(0u, 0u, 1u, __float_as_uint(mn));
    return;
  }
  unsigned b4[4]; unsigned s4 = 0;
  #pragma unroll
  for (int j = 0; j < 4; ++j) {
    const int di = tid * 4 + j;
    const int bin = role ? di : (NBIN - 1 - di);
    b4[j] = ghist[c * 2 * NBIN + role * NBIN + bin];
    s4 += b4[j];
  }
  unsigned xs = s4;
  const int lane = tid & 63, wid = tid >> 6;
  #pragma unroll
  for (int d = 1; d < 64; d <<= 1) {
    const unsigned t = (unsigned)__shfl_up((int)xs, d, 64);
    if (lane >= d) xs += t;
  }
  if (lane == 63) wsum[wid] = xs;
  __syncthreads();
  unsigned off = 0;
  #pragma unroll
  for (int w = 0; w < 4; ++w) if (w < wid) off += wsum[w];
  const unsigned gcum = xs + off;
  const unsigned gprev = gcum - s4;
  if (gcum >= KSEL && gprev < KSEL) {
    unsigned run = gprev; int Tdi = tid * 4; unsigned strict = gprev;
    #pragma unroll
    for (int j = 0; j < 4; ++j) {
      if (run + b4[j] >= KSEL) { Tdi = tid * 4 + j; strict = run; break; }
      run += b4[j];
    }
    const int T = role ? Tdi : (NBIN - 1 - Tdi);
    trec[c * 2 + role] = make_uint4((unsigned)T, strict, 0u, 0u);
  }
}

// ------------------------------------------------- strict sums + boundary compaction
__global__ __launch_bounds__(256) void k_finalsum(const float* __restrict__ dist,
                                                  const int* __restrict__ y,
                                                  const unsigned* __restrict__ stats,
                                                  const uint4* __restrict__ trec,
                                                  float* __restrict__ ssum,
                                                  int* __restrict__ bcnt,
                                                  float* __restrict__ bbuf) {
  __shared__ float red[2][4];
  const int tid = threadIdx.x;
  const int c = blockIdx.x >> 4;
  const int n0 = (blockIdx.x & 15) * 4096;
  const uint4 rp = trec[c * 2 + 0];
  const uint4 rn = trec[c * 2 + 1];
  const float mnp = __uint_as_float(stats[c * 4 + 0]);
  const float mxp = __uint_as_float(stats[c * 4 + 1]);
  const float mnn = __uint_as_float(stats[c * 4 + 2]);
  const float mxn = __uint_as_float(stats[c * 4 + 3]);
  const float scp = (mxp > mnp) ? (float)NBIN / (mxp - mnp) : 0.f;
  const float scn = (mxn > mnn) ? (float)NBIN / (mxn - mnn) : 0.f;
  const int Tp = (int)rp.x, Tn = (int)rn.x;
  const bool dop = rp.z != 0u, don = rn.z != 0u;
  const float4* __restrict__ row4 = (const float4*)(dist + (size_t)c * N_SAMP + n0);
  const int4* __restrict__ y4 = (const int4*)(y + n0);
  float sp = 0.f, sn = 0.f;
  #pragma unroll
  for (int i = 0; i < 4; ++i) {
    const int idx = i * 256 + tid;
    const float4 v = row4[idx];
    const int4 yy = y4[idx];
    const float vv[4] = {v.x, v.y, v.z, v.w};
    const int ys[4] = {yy.x, yy.y, yy.z, yy.w};
    #pragma unroll
    for (int j = 0; j < 4; ++j) {
      const float v1 = vv[j];
      if (ys[j] == c) {
        if (!dop) {
          const int b = binOf(v1, mnp, scp);
          if (b > Tp) sp += v1;
          else if (b == Tp) {
            const int p = atomicAdd(&bcnt[c * 2 + 0], 1);
            if (p < BCAP) bbuf[(c * 2 + 0) * BCAP + p] = v1;
          }
        }
      } else {
        if (!don) {
          const int b = binOf(v1, mnn, scn);
          if (b < Tn) sn += v1;
          else if (b == Tn) {
            const int p = atomicAdd(&bcnt[c * 2 + 1], 1);
            if (p < BCAP) bbuf[(c * 2 + 1) * BCAP + p] = v1;
          }
        }
      }
    }
  }
  sp = wredAddF(sp); sn = wredAddF(sn);
  const int wid = tid >> 6;
  if ((tid & 63) == 0) { red[0][wid] = sp; red[1][wid] = sn; }
  __syncthreads();
  if (tid == 0) {
    float tp = red[0][0] + red[0][1] + red[0][2] + red[0][3];
    float tn = red[1][0] + red[1][1] + red[1][2] + red[1][3];
    if (tp != 0.f) atomicAdd(&ssum[c * 2 + 0], tp);
    if (tn != 0.f) atomicAdd(&ssum[c * 2 + 1], tn);
  }
}

// ------------------------------------------------- exact boundary resolve
__global__ __launch_bounds__(256) void k_final(const uint4* __restrict__ trec,
                                               const float* __restrict__ ssum,
                                               const int* __restrict__ bcnt,
                                               const float* __restrict__ bbuf,
                                               float* __restrict__ means) {
  __shared__ float s[256];
  __shared__ float red[4];
  const int tid = threadIdx.x;
  const int c = blockIdx.x >> 1;
  const int role = blockIdx.x & 1;
  const uint4 r = trec[c * 2 + role];
  if (r.z != 0u) {
    if (tid == 0) means[role * 64 + c] = __uint_as_float(r.w);
    return;
  }
  int cnt = bcnt[c * 2 + role];
  cnt = cnt < BCAP ? cnt : BCAP;
  int need = KSEL - (int)r.y;
  need = need < cnt ? need : cnt;
  const float pad = role ? __uint_as_float(0x7F800000u) : __uint_as_float(0xFF800000u);
  s[tid] = (tid < cnt) ? bbuf[(c * 2 + role) * BCAP + tid] : pad;
  __syncthreads();
  for (int k = 2; k <= 256; k <<= 1) {
    for (int j = k >> 1; j > 0; j >>= 1) {
      const int ixj = tid ^ j;
      const float a = s[tid];
      const float b = s[ixj];
      __syncthreads();
      if (ixj > tid) {
        const bool asc = ((tid & k) == 0);
        if ((a > b) == asc) { s[tid] = b; s[ixj] = a; }
      }
      __syncthreads();
    }
  }
  float v = 0.f;
  if (role) { if (tid < need) v = s[tid]; }
  else      { if (tid >= 256 - need) v = s[tid]; }
  v = wredAddF(v);
  if ((tid & 63) == 0) red[tid >> 6] = v;
  __syncthreads();
  if (tid == 0) {
    const float total = ssum[c * 2 + role] + red[0] + red[1] + red[2] + red[3];
    means[role * 64 + c] = total * (1.0f / (float)KSEL);
  }
}

// ------------------------------------------------- final loss
__global__ __launch_bounds__(64) void k_loss(const float* __restrict__ means, float* __restrict__ out) {
  const int c = threadIdx.x;
  float pc = fmaxf(1.0f + means[c] - means[64 + c], 0.0f);
  #pragma unroll
  for (int o = 32; o; o >>= 1) pc += __shfl_down(pc, o, 64);
  if (c == 0) out[0] = pc * (1.0f / 4096.0f);
}

// ----------------------------------------------------------------------
extern "C" void kernel_launch(void* const* d_in, const int* in_sizes, int n_in,
                              void* d_out, int out_size, void* d_ws, size_t ws_size,
                              hipStream_t stream) {
  const float* x = (const float*)d_in[0];
  const int* y = (const int*)d_in[1];
  float* out = (float*)d_out;
  char* w = (char*)d_ws;
  int* counts          = (int*)(w + OFF_COUNTS);
  float* csum          = (float*)(w + OFF_CSUM);
  unsigned short* cenb = (unsigned short*)(w + OFF_CENTERS);
  float* c2            = (float*)(w + OFF_C2);
  float* means         = (float*)(w + OFF_MEANS);
  float* dist          = (float*)(w + OFF_DIST);
  unsigned* stats      = (unsigned*)(w + OFF_STATS);
  unsigned* ghist      = (unsigned*)(w + OFF_HIST);
  uint4* trec          = (uint4*)(w + OFF_THRESH);
  float* ssum          = (float*)(w + OFF_SSUM);
  int* bcnt            = (int*)(w + OFF_BCNT);
  float* bbuf          = (float*)(w + OFF_BBUF);

  hipLaunchKernelGGL(k_init, dim3(512), dim3(256), 0, stream, counts, csum, stats, ghist, ssum, bcnt);
  hipLaunchKernelGGL(k_class_sums, dim3(1024), dim3(256), 0, stream, x, y, csum, counts);
  hipLaunchKernelGGL(k_centers, dim3(64), dim3(64), 0, stream, csum, counts, cenb, c2);
  hipLaunchKernelGGL(k_dist_mfma, dim3(N_SAMP / 128), dim3(512), 0, stream, x, cenb, c2, dist);
  hipLaunchKernelGGL(k_stats, dim3(1024), dim3(256), 0, stream, dist, y, stats);
  hipLaunchKernelGGL(k_hist, dim3(1024), dim3(256), 0, stream, dist, y, stats, ghist);
  hipLaunchKernelGGL(k_thresh, dim3(128), dim3(256), 0, stream, ghist, stats, trec);
  hipLaunchKernelGGL(k_finalsum, dim3(1024), dim3(256), 0, stream, dist, y, stats, trec, ssum, bcnt, bbuf);
  hipLaunchKernelGGL(k_final, dim3(128), dim3(256), 0, stream, trec, ssum, bcnt, bbuf, means);
  hipLaunchKernelGGL(k_loss, dim3(1), dim3(64), 0, stream, means, out);
}